// Round 7
// baseline (456.161 us; speedup 1.0000x reference)
//
#include <hip/hip_runtime.h>
#include <math.h>

// Problem constants (reference: T=16384, H=2048, E=256)
#define H_      2048
#define E_      256
#define T_TILE  32      // tokens per block (8 per wave, 4 waves) -> grid 512
#define KC      32      // K-chunk (2 SSE 16-blocks); w staged in LDS, h in VGPRs
#define TOPK    8
#define KGROUP  4

typedef float f2 __attribute__((ext_vector_type(2)));

// Packed fp32 FMA with the h pair as a 64-bit SGPR source (VOP3P allows one
// SGPR operand). h pairs come from v_readlane (wave-uniform broadcast on the
// VALU pipe) -> the 64 h-broadcast ds_reads per wave-chunk leave the LDS pipe
// entirely. Per-component IEEE RN fma, identical chain order -> bit-identical
// to R6's accepted numerics.
__device__ __forceinline__ void pk_fma_s(f2& a, unsigned long long h, f2 w) {
    asm("v_pk_fma_f32 %0, %1, %2, %0" : "+v"(a) : "s"(h), "v"(w));
}

// LDS: ONLY the w tile. Expert-major [E][KC], slot-swizzled at float4
// granularity: stored slot s of row e holds global float4-slot s^((e>>2)&7).
// Staged by global_load_lds (linear dest) with pre-swizzled SOURCE addresses
// (both-sides-or-neither); read-side ds_read_b128 applies the same XOR.
struct GemmSmem { float w[E_][KC]; };        // 32768 B
union SMem {
    GemmSmem g;
    float logits[T_TILE][E_];                // 32768 B
};

// (256,1): LDS (32KB) + grid (2 blocks/CU) set occupancy; no VGPR cap ->
// no spill risk (R4 lesson). VGPR <= ~170 keeps 2 blocks/CU regardless.
__global__ __launch_bounds__(256, 1)
void router_kernel(const float* __restrict__ hp,
                   const float* __restrict__ wp,
                   const float* __restrict__ bp,
                   float* __restrict__ out, int T)
{
#pragma clang fp contract(off)
    __shared__ SMem sm;
    const int tid  = threadIdx.x;
    const int t0   = blockIdx.x * T_TILE;
    const int lane = tid & 63;
    const int eq   = lane;          // expert quad: experts eq*4 .. eq*4+3
    const int wv   = tid >> 6;      // wave id: tokens wv*8 .. wv*8+7
    const int wvu  = __builtin_amdgcn_readfirstlane(wv);

    // acc[i][j]: pair 0 = k%4 in {0,1}, pair 1 = k%4 in {2,3}; fp32 pk_fma
    // accumulation (fused), final hadd tree below. Same chain order as R6.
    f2 acc[8][4][2];   // [token i][expert j][pair]
#pragma unroll
    for (int i = 0; i < 8; ++i)
#pragma unroll
        for (int j = 0; j < 4; ++j) {
            acc[i][j][0] = (f2){0.f, 0.f};
            acc[i][j][1] = (f2){0.f, 0.f};
        }

    // chunk-invariant compute-side LDS base (single buffer)
    const float* wlds = &sm.g.w[eq << 2][0];
    const int    swx  = eq & 7;            // read-side XOR key = (e>>2)&7

    // h lives in VGPRs: the wave's 64 lanes hold its 8 tokens x 8 slots,
    // one float4 per lane (token = lane>>3, slot = lane&7). Coalesced
    // per-lane global loads; broadcast in-compute via v_readlane.
    const float* hsrc0 = hp + (size_t)(t0 + (wvu << 3) + (lane >> 3)) * H_
                       + ((lane & 7) << 2);

    // prologue: h for chunk 0
    float4 hv = *(const float4*)(hsrc0);

    for (int ch = 0; ch < H_ / KC; ++ch) {
        const int k0 = ch * KC;

        // ---- stage w tile: 8 wave-ops x 1024B. Op r covers rows
        // E0=(r*4+wv)*8 .. +7; lane l -> row E0+(l>>3), stored slot l&7.
        // Source slot pre-XORed with key=(e>>2)&7 so stored slot s holds
        // global slot s^key (read side undoes it with the same XOR).
#pragma unroll
        for (int r = 0; r < 8; ++r) {
            const int E0 = (r * 4 + wvu) * 8;
            const int e  = E0 + (lane >> 3);
            const int gs = (lane & 7) ^ ((e >> 2) & 7);
            const float* src = wp + (size_t)e * H_ + k0 + (gs << 2);
            __builtin_amdgcn_global_load_lds(
                (const __attribute__((address_space(1))) void*)src,
                (__attribute__((address_space(3))) void*)&sm.g.w[E0][0],
                16, 0, 0);
        }
        __syncthreads();   // vmcnt(0) drain -> w tile visible to all waves

        // ---- prefetch h for the next chunk (registers only, no hazard);
        // clamped at the tail (reload of chunk 63, values unused).
        const int chn = (ch < H_ / KC - 1) ? ch + 1 : ch;
        float4 hv_next = *(const float4*)(hsrc0 + chn * KC);

        // ---- compute: 8 float4-slots; S order identical to R6.
#pragma unroll
        for (int mb = 0; mb < 2; ++mb) {
#pragma unroll
            for (int jj = 3; jj >= 0; --jj) {
                const int S = (mb << 2) + jj;           // global float4-slot
                const float* wr = wlds + ((S ^ swx) << 2);
                float4 wreg[4];
                wreg[0] = *(const float4*)(wr);
                wreg[1] = *(const float4*)(wr + KC);
                wreg[2] = *(const float4*)(wr + 2 * KC);
                wreg[3] = *(const float4*)(wr + 3 * KC);
#pragma unroll
                for (int i = 0; i < 8; ++i) {
                    // broadcast token i / slot S from lane i*8+S (exact)
                    const int sl = i * 8 + S;
                    const unsigned hx = __builtin_amdgcn_readlane(
                        __float_as_uint(hv.x), sl);
                    const unsigned hy = __builtin_amdgcn_readlane(
                        __float_as_uint(hv.y), sl);
                    const unsigned hz = __builtin_amdgcn_readlane(
                        __float_as_uint(hv.z), sl);
                    const unsigned hw = __builtin_amdgcn_readlane(
                        __float_as_uint(hv.w), sl);
                    const unsigned long long hA =
                        (unsigned long long)hx | ((unsigned long long)hy << 32);
                    const unsigned long long hB =
                        (unsigned long long)hz | ((unsigned long long)hw << 32);
#pragma unroll
                    for (int j = 0; j < 4; ++j) {
                        const f2 wA = {wreg[j].x, wreg[j].y};
                        const f2 wB = {wreg[j].z, wreg[j].w};
                        pk_fma_s(acc[i][j][0], hA, wA);
                        pk_fma_s(acc[i][j][1], hB, wB);
                    }
                }
            }
        }
        hv = hv_next;
        __syncthreads();   // all w reads done before next stage overwrites
    }

    // ---- hadd tree (v0+v1)+(v2+v3) + dump fp32 logits into unioned tile
#pragma unroll
    for (int i = 0; i < 8; ++i)
#pragma unroll
        for (int j = 0; j < 4; ++j)
            sm.logits[(wv << 3) + i][(eq << 2) + j] =
                ((acc[i][j][0].x + acc[i][j][0].y) +
                 (acc[i][j][1].x + acc[i][j][1].y));
    __syncthreads();

    // ================= routing: each wave handles its 8 tokens ==============
    float* out_idx = out;                       // [T][8] indices as floats
    float* out_w   = out + (size_t)T * TOPK;    // [T][8] weights

    const float b0 = bp[lane * 4 + 0];
    const float b1 = bp[lane * 4 + 1];
    const float b2 = bp[lane * 4 + 2];
    const float b3 = bp[lane * 4 + 3];

    for (int tt = 0; tt < 8; ++tt) {
        const int tl = (wv << 3) + tt;
        const int t  = t0 + tl;

        float4 lg = *(const float4*)(&sm.logits[tl][lane * 4]);
        // numpy graph: s = 1/(1+exp(-x)), fp32 add + fp32 division;
        // exp in fp64, correctly rounded to fp32.
        const float E0 = (float)exp(-(double)lg.x);
        const float E1 = (float)exp(-(double)lg.y);
        const float E2 = (float)exp(-(double)lg.z);
        const float E3 = (float)exp(-(double)lg.w);
        const float s0 = __fdiv_rn(1.0f, __fadd_rn(1.0f, E0));
        const float s1 = __fdiv_rn(1.0f, __fadd_rn(1.0f, E1));
        const float s2 = __fdiv_rn(1.0f, __fadd_rn(1.0f, E2));
        const float s3 = __fdiv_rn(1.0f, __fadd_rn(1.0f, E3));
        // scores_for_choice = score + bias (fp32 add; bias == 0)
        const float f0 = s0 + b0, f1 = s1 + b1, f2 = s2 + b2, f3 = s3 + b3;

        // ---- per-lane top-2 of its 4 sfc values
        float a = fmaxf(f0, f1), b = fminf(f0, f1);
        if (f2 > a) { b = a; a = f2; } else b = fmaxf(b, f2);
        if (f3 > a) { b = a; a = f3; } else b = fmaxf(b, f3);
        // ---- reduce top-2 across the 8 lanes of this group
#pragma unroll
        for (int m = 1; m <= 4; m <<= 1) {
            float oa = __shfl_xor(a, m);
            float ob = __shfl_xor(b, m);
            float na, nb;
            if (a >= oa) { na = a;  nb = fmaxf(oa, b); }
            else         { na = oa; nb = fmaxf(a, ob); }
            a = na; b = nb;
        }
        const float gsc = a + b;   // group score (fp32)

        // gather all 8 group scores to every lane
        float g0 = __shfl(gsc,  0), g1 = __shfl(gsc,  8);
        float g2 = __shfl(gsc, 16), g3 = __shfl(gsc, 24);
        float g4 = __shfl(gsc, 32), g5 = __shfl(gsc, 40);
        float g6 = __shfl(gsc, 48), g7 = __shfl(gsc, 56);

        // ---- top-4 groups (stable: lower index wins ties via strict >)
        unsigned gmask = 0;
#pragma unroll
        for (int r = 0; r < KGROUP; ++r) {
            float best = g0; int bg = 0;
            if (g1 > best) { best = g1; bg = 1; }
            if (g2 > best) { best = g2; bg = 2; }
            if (g3 > best) { best = g3; bg = 3; }
            if (g4 > best) { best = g4; bg = 4; }
            if (g5 > best) { best = g5; bg = 5; }
            if (g6 > best) { best = g6; bg = 6; }
            if (g7 > best) { best = g7; bg = 7; }
            gmask |= (1u << bg);
            g0 = (bg == 0) ? -1.f : g0;  g1 = (bg == 1) ? -1.f : g1;
            g2 = (bg == 2) ? -1.f : g2;  g3 = (bg == 3) ? -1.f : g3;
            g4 = (bg == 4) ? -1.f : g4;  g5 = (bg == 5) ? -1.f : g5;
            g6 = (bg == 6) ? -1.f : g6;  g7 = (bg == 7) ? -1.f : g7;
        }

        // ---- masked sfc (unselected groups -> 0.0, matching np.where)
        const int  myg  = lane >> 3;
        const bool keep = (gmask >> myg) & 1u;
        float v0 = keep ? f0 : 0.f, v1 = keep ? f1 : 0.f;
        float v2 = keep ? f2 : 0.f, v3 = keep ? f3 : 0.f;

        // ---- top-8: 8 rounds of 64-lane butterfly argmax, fp32 values,
        //      exact-equality ties -> lower expert index (stable top_k)
        int   isel[TOPK];
        float ssel[TOPK];
#pragma unroll
        for (int r = 0; r < TOPK; ++r) {
            float bv = v0; int bj = 0; float bs = s0;
            if (v1 > bv) { bv = v1; bj = 1; bs = s1; }
            if (v2 > bv) { bv = v2; bj = 2; bs = s2; }
            if (v3 > bv) { bv = v3; bj = 3; bs = s3; }
            float cv = bv; int ci = lane * 4 + bj; float cs = bs;
#pragma unroll
            for (int m = 1; m < 64; m <<= 1) {
                float ov = __shfl_xor(cv, m);
                int   oi = __shfl_xor(ci, m);
                float os = __shfl_xor(cs, m);
                if (ov > cv || (ov == cv && oi < ci)) { cv = ov; ci = oi; cs = os; }
            }
            isel[r] = ci; ssel[r] = cs;
            if ((ci >> 2) == lane) {       // owner removes the winner
                const int sl = ci & 3;
                v0 = (sl == 0) ? -1.f : v0;
                v1 = (sl == 1) ? -1.f : v1;
                v2 = (sl == 2) ? -1.f : v2;
                v3 = (sl == 3) ? -1.f : v3;
            }
        }

        // ---- normalize + scale in fp32: w = (w / (sum + 1e-20)) * 2.5
        // np pairwise 8-sum: ((w0+w1)+(w2+w3)) + ((w4+w5)+(w6+w7))
        const float sum = __fadd_rn(
            __fadd_rn(__fadd_rn(ssel[0], ssel[1]), __fadd_rn(ssel[2], ssel[3])),
            __fadd_rn(__fadd_rn(ssel[4], ssel[5]), __fadd_rn(ssel[6], ssel[7])));
        const float denom = __fadd_rn(sum, 1e-20f);
        if (lane == 0) {
#pragma unroll
            for (int r = 0; r < TOPK; ++r) {
                out_idx[(size_t)t * TOPK + r] = (float)isel[r];
                out_w  [(size_t)t * TOPK + r] =
                    __fmul_rn(__fdiv_rn(ssel[r], denom), 2.5f);
            }
        }
    }
}

extern "C" void kernel_launch(void* const* d_in, const int* in_sizes, int n_in,
                              void* d_out, int out_size, void* d_ws, size_t ws_size,
                              hipStream_t stream) {
    const float* hs = (const float*)d_in[0];
    const float* w  = (const float*)d_in[1];
    const float* b  = (const float*)d_in[2];
    const int E = in_sizes[2];          // 256
    const int H = in_sizes[1] / E;      // 2048
    const int T = in_sizes[0] / H;      // 16384
    (void)n_in; (void)d_ws; (void)ws_size; (void)out_size; (void)E; (void)H;

    dim3 grid(T / T_TILE);
    router_kernel<<<grid, 256, 0, stream>>>(hs, w, b, (float*)d_out, T);
}